// Round 4
// baseline (1294.025 us; speedup 1.0000x reference)
//
#include <hip/hip_runtime.h>

// Graph TransformerConv x2 + MLP head. CSR, atomic-free, factorized edge-MLP:
//   logit = (q·k + (We·q)·ea)/sqrt(C);  agg = sum(p*v) + We^T * sum(p*ea)
// N=50000, E=800000, F_NODE=128, F_EDGE=32, H=4, C1=32, C2=16.

constexpr int NN = 50000;
constexpr int NE = 800000;

// ---- generic small GEMM: C[n,M] = A[n,K] @ W[K,M] + b ----
template <int K, int M>
__global__ __launch_bounds__(256) void gemm_bias(
    const float* __restrict__ A, const float* __restrict__ W,
    const float* __restrict__ b, float* __restrict__ C, int n) {
  constexpr int RB = 64;
  constexpr int RSTEP = 256 / M;
  __shared__ float As[RB][K];
  const int bi = blockIdx.x * RB;
  for (int idx = threadIdx.x; idx < RB * K; idx += 256) {
    int r = idx / K, c = idx - r * K;
    int gr = bi + r;
    As[r][c] = (gr < n) ? A[(size_t)gr * K + c] : 0.f;
  }
  __syncthreads();
  const int col = threadIdx.x % M;
  const int r0 = threadIdx.x / M;
  const float bias = b[col];
  for (int rbase = r0; rbase < RB; rbase += RSTEP * 4) {
    float a0 = bias, a1 = bias, a2 = bias, a3 = bias;
#pragma unroll 8
    for (int kk = 0; kk < K; ++kk) {
      float w = W[kk * M + col];
      a0 = fmaf(As[rbase][kk], w, a0);
      a1 = fmaf(As[rbase + RSTEP][kk], w, a1);
      a2 = fmaf(As[rbase + 2 * RSTEP][kk], w, a2);
      a3 = fmaf(As[rbase + 3 * RSTEP][kk], w, a3);
    }
    if (bi + rbase < n)              C[(size_t)(bi + rbase) * M + col] = a0;
    if (bi + rbase + RSTEP < n)      C[(size_t)(bi + rbase + RSTEP) * M + col] = a1;
    if (bi + rbase + 2 * RSTEP < n)  C[(size_t)(bi + rbase + 2 * RSTEP) * M + col] = a2;
    if (bi + rbase + 3 * RSTEP < n)  C[(size_t)(bi + rbase + 3 * RSTEP) * M + col] = a3;
  }
}

// ---- fold Wq,bq,We into Wqe [(K+1) x 128], col layout h*32+f; last row = bias ----
template <int K, int HC, int C>
__global__ __launch_bounds__(256) void make_wqe_k(
    const float* __restrict__ Wq, const float* __restrict__ bq,
    const float* __restrict__ We, float* __restrict__ Wqe) {
  const int idx = blockIdx.x * 256 + threadIdx.x;
  if (idx >= (K + 1) * 128) return;
  const int r = idx >> 7;
  const int hf = idx & 127;
  const int h = hf >> 5, f = hf & 31;
  float acc = 0.f;
#pragma unroll
  for (int c = 0; c < C; ++c) {
    const float wv = We[f * HC + h * C + c];
    const float qv = (r < K) ? Wq[r * HC + h * C + c] : bq[h * C + c];
    acc = fmaf(qv, wv, acc);
  }
  Wqe[idx] = acc;
}

// ---- CSR build ----
__global__ __launch_bounds__(256) void hist_k(const int* __restrict__ dst,
                                              int* __restrict__ deg, int nE) {
  const int i = blockIdx.x * 256 + threadIdx.x;
  if (i < nE) atomicAdd(&deg[dst[i]], 1);
}

__global__ __launch_bounds__(1024) void scan_k(const int* __restrict__ deg,
                                               int* __restrict__ rowptr,
                                               int* __restrict__ cursor, int n) {
  __shared__ int part[1024];
  const int t = threadIdx.x;
  const int chunk = (n + 1023) / 1024;
  const int lo = t * chunk;
  const int hi = min(lo + chunk, n);
  int s = 0;
  for (int i = lo; i < hi; ++i) s += deg[i];
  part[t] = s;
  __syncthreads();
  for (int off = 1; off < 1024; off <<= 1) {
    int tmp = (t >= off) ? part[t - off] : 0;
    __syncthreads();
    part[t] += tmp;
    __syncthreads();
  }
  int base = (t == 0) ? 0 : part[t - 1];
  for (int i = lo; i < hi; ++i) {
    rowptr[i] = base;
    cursor[i] = base;
    base += deg[i];
  }
  if (t == 1023) rowptr[n] = part[1023];
}

__global__ __launch_bounds__(256) void scatter_k(
    const int* __restrict__ src, const int* __restrict__ dst,
    int* __restrict__ cursor, int* __restrict__ csr_src,
    int* __restrict__ csr_eid, int nE) {
  const int i = blockIdx.x * 256 + threadIdx.x;
  if (i < nE) {
    const int d = dst[i];
    const int pos = atomicAdd(&cursor[d], 1);
    csr_src[pos] = src[i];
    csr_eid[pos] = i;
  }
}

// ---- edge-parallel logits: one wave per edge, fully independent ----
template <int HC>
__global__ __launch_bounds__(256) void edge_logits2_k(
    const float* __restrict__ q, const float* __restrict__ k,
    const float* __restrict__ qe, const float* __restrict__ ea,
    const int* __restrict__ src, const int* __restrict__ dst,
    float* __restrict__ logits, int nE, float inv) {
  const int e = (blockIdx.x * 256 + threadIdx.x) >> 6;
  const int lane = threadIdx.x & 63;
  if (e >= nE) return;
  const int s = __builtin_amdgcn_readfirstlane(src[e]);
  const int d = __builtin_amdgcn_readfirstlane(dst[e]);
  const int gl = lane & 15, h = lane >> 4;
  constexpr int CPL = HC / 64;
  const int ch0 = lane * CPL;
  float dot;
  if constexpr (CPL == 2) {
    const float2 qv = *(const float2*)&q[(size_t)d * HC + ch0];
    const float2 kv = *(const float2*)&k[(size_t)s * HC + ch0];
    dot = qv.x * kv.x + qv.y * kv.y;
  } else {
    dot = q[(size_t)d * HC + ch0] * k[(size_t)s * HC + ch0];
  }
  const float2 qev = *(const float2*)&qe[(size_t)d * 128 + h * 32 + 2 * gl];
  const float2 eav = *(const float2*)&ea[(size_t)e * 32 + 2 * gl];
  dot = fmaf(qev.x, eav.x, dot);
  dot = fmaf(qev.y, eav.y, dot);
#pragma unroll
  for (int off = 1; off < 16; off <<= 1) dot += __shfl_xor(dot, off);
  if (gl == 0) logits[(size_t)e * 4 + h] = dot * inv;
}

// ---- dst-centric aggregate: chunked (16-edge) parallel online softmax ----
template <int HC, int C, bool FINAL>
__global__ __launch_bounds__(256) void tconv_agg2_k(
    const float* __restrict__ v, const float* __restrict__ ea,
    const float* __restrict__ We, const int* __restrict__ rowptr,
    const int* __restrict__ csr_src, const int* __restrict__ csr_eid,
    const float* __restrict__ logits, const float* __restrict__ skip,
    const float* __restrict__ W3, const float* __restrict__ b3,
    const float* __restrict__ W4, const float* __restrict__ b4,
    float* __restrict__ out, int n) {
  const int d = (blockIdx.x * 256 + threadIdx.x) >> 6;
  const int lane = threadIdx.x & 63;
  if (d >= n) return;
  constexpr int CPL = HC / 64;
  const int gl = lane & 15;
  const int h = lane >> 4;
  const int ch0 = lane * CPL;

  float m = -INFINITY, sden = 0.f;
  float acc0 = 0.f, acc1 = 0.f, pea0 = 0.f, pea1 = 0.f;
  const int p0 = rowptr[d], p1 = rowptr[d + 1];

  for (int base = p0; base < p1; base += 16) {
    const int cnt = min(16, p1 - base);
    int sn_l = 0, eid_l = 0;
    float l_l = -INFINITY;
    if (gl < cnt) {
      sn_l = csr_src[base + gl];
      eid_l = csr_eid[base + gl];
      l_l = logits[(size_t)eid_l * 4 + h];
    }
    // chunk max / exp / sum — parallel across the 16 lanes
    float cmax = l_l;
#pragma unroll
    for (int off = 1; off < 16; off <<= 1) cmax = fmaxf(cmax, __shfl_xor(cmax, off));
    const float newm = fmaxf(m, cmax);
    const float scale = __expf(m - newm);
    const float p_l = __expf(l_l - newm);   // -inf -> 0 for tail lanes
    float csum = p_l;
#pragma unroll
    for (int off = 1; off < 16; off <<= 1) csum += __shfl_xor(csum, off);
    sden = sden * scale + csum;
    acc0 *= scale; acc1 *= scale; pea0 *= scale; pea1 *= scale;
    m = newm;
    // dependency-free gather-FMA loop
    if (cnt == 16) {
#pragma unroll
      for (int j = 0; j < 16; ++j) {
        const float pj = __shfl(p_l, j, 16);
        const int snj = __shfl(sn_l, j, 16);
        const int eidj = __shfl(eid_l, j, 16);
        const float2 eav = *(const float2*)&ea[(size_t)eidj * 32 + 2 * gl];
        if constexpr (CPL == 2) {
          const float2 vv = *(const float2*)&v[(size_t)snj * HC + ch0];
          acc0 = fmaf(pj, vv.x, acc0);
          acc1 = fmaf(pj, vv.y, acc1);
        } else {
          acc0 = fmaf(pj, v[(size_t)snj * HC + ch0], acc0);
        }
        pea0 = fmaf(pj, eav.x, pea0);
        pea1 = fmaf(pj, eav.y, pea1);
      }
    } else {
      for (int j = 0; j < cnt; ++j) {
        const float pj = __shfl(p_l, j, 16);
        const int snj = __shfl(sn_l, j, 16);
        const int eidj = __shfl(eid_l, j, 16);
        const float2 eav = *(const float2*)&ea[(size_t)eidj * 32 + 2 * gl];
        if constexpr (CPL == 2) {
          const float2 vv = *(const float2*)&v[(size_t)snj * HC + ch0];
          acc0 = fmaf(pj, vv.x, acc0);
          acc1 = fmaf(pj, vv.y, acc1);
        } else {
          acc0 = fmaf(pj, v[(size_t)snj * HC + ch0], acc0);
        }
        pea0 = fmaf(pj, eav.x, pea0);
        pea1 = fmaf(pj, eav.y, pea1);
      }
    }
  }

  const float rs = (sden > 0.f) ? 1.f / sden : 0.f;
  acc0 *= rs; acc1 *= rs; pea0 *= rs; pea1 *= rs;

  // We^T correction: acc_ch += sum_f We[f, ch] * pea_h[f]  (once per node)
  float cor0 = 0.f, cor1 = 0.f;
#pragma unroll
  for (int ff = 0; ff < 16; ++ff) {
    const float pf0 = __shfl(pea0, ff, 16);
    const float pf1 = __shfl(pea1, ff, 16);
    if constexpr (CPL == 2) {
      const float2 w0 = *(const float2*)&We[(2 * ff) * HC + ch0];
      const float2 w1 = *(const float2*)&We[(2 * ff + 1) * HC + ch0];
      cor0 = fmaf(pf0, w0.x, cor0); cor0 = fmaf(pf1, w1.x, cor0);
      cor1 = fmaf(pf0, w0.y, cor1); cor1 = fmaf(pf1, w1.y, cor1);
    } else {
      cor0 = fmaf(pf0, We[(2 * ff) * HC + ch0], cor0);
      cor0 = fmaf(pf1, We[(2 * ff + 1) * HC + ch0], cor0);
    }
  }
  acc0 += cor0; acc1 += cor1;

  // head-mean across the 4 groups
  acc0 += __shfl_xor(acc0, 16); acc0 += __shfl_xor(acc0, 32);
  if constexpr (CPL == 2) { acc1 += __shfl_xor(acc1, 16); acc1 += __shfl_xor(acc1, 32); }

  if constexpr (!FINAL) {
    if (lane < 16) {
      const int c0 = 2 * lane;
      out[(size_t)d * 32 + c0]     = fmaxf(acc0 * 0.25f + skip[(size_t)d * 32 + c0], 0.f);
      out[(size_t)d * 32 + c0 + 1] = fmaxf(acc1 * 0.25f + skip[(size_t)d * 32 + c0 + 1], 0.f);
    }
  } else {
    const int c = lane & 15;
    const float h2 = fmaxf(acc0 * 0.25f + skip[(size_t)d * 16 + c], 0.f);
    const int j = lane & 31;
    float t3 = b3[j];
#pragma unroll
    for (int cc = 0; cc < 16; ++cc)
      t3 = fmaf(__shfl(h2, cc), W3[cc * 32 + j], t3);
    t3 = fmaxf(t3, 0.f);
    float o0 = t3 * W4[j * 2 + 0];
    float o1 = t3 * W4[j * 2 + 1];
#pragma unroll
    for (int off = 1; off < 32; off <<= 1) {
      o0 += __shfl_xor(o0, off);
      o1 += __shfl_xor(o1, off);
    }
    if (lane == 0) {
      out[(size_t)d * 2 + 0] = o0 + b4[0];
      out[(size_t)d * 2 + 1] = o1 + b4[1];
    }
  }
}

extern "C" void kernel_launch(void* const* d_in, const int* in_sizes, int n_in,
                              void* d_out, int out_size, void* d_ws, size_t ws_size,
                              hipStream_t stream) {
  const float* x   = (const float*)d_in[0];
  const int*   ei  = (const int*)d_in[1];
  const float* ea  = (const float*)d_in[2];
  const float* Wq1 = (const float*)d_in[3];  const float* bq1 = (const float*)d_in[4];
  const float* Wk1 = (const float*)d_in[5];  const float* bk1 = (const float*)d_in[6];
  const float* Wv1 = (const float*)d_in[7];  const float* bv1 = (const float*)d_in[8];
  const float* We1 = (const float*)d_in[9];
  const float* Ws1 = (const float*)d_in[10]; const float* bs1 = (const float*)d_in[11];
  const float* Wq2 = (const float*)d_in[12]; const float* bq2 = (const float*)d_in[13];
  const float* Wk2 = (const float*)d_in[14]; const float* bk2 = (const float*)d_in[15];
  const float* Wv2 = (const float*)d_in[16]; const float* bv2 = (const float*)d_in[17];
  const float* We2 = (const float*)d_in[18];
  const float* Ws2 = (const float*)d_in[19]; const float* bs2 = (const float*)d_in[20];
  const float* W3  = (const float*)d_in[21]; const float* b3  = (const float*)d_in[22];
  const float* W4  = (const float*)d_in[23]; const float* b4  = (const float*)d_in[24];
  const int* src = ei;
  const int* dst = ei + NE;

  // workspace layout
  float* wsf    = (float*)d_ws;
  float* q      = wsf;                        // N*128
  float* kbuf   = q + (size_t)NN * 128;       // N*128
  float* vbuf   = kbuf + (size_t)NN * 128;    // N*128
  float* qe     = vbuf + (size_t)NN * 128;    // N*128
  float* skip   = qe + (size_t)NN * 128;      // N*32
  float* h1     = skip + (size_t)NN * 32;     // N*32
  float* logits = h1 + (size_t)NN * 32;       // E*4
  float* Wqe    = logits + (size_t)NE * 4;    // 129*128 (max)
  int* deg      = (int*)(Wqe + 129 * 128);    // N
  int* rowptr   = deg + NN;                   // N+1
  int* cursor   = rowptr + NN + 1;            // N
  int* csr_src  = cursor + NN;                // E
  int* csr_eid  = csr_src + NE;               // E

  const int gemmGrid = (NN + 63) / 64;
  const int edgeGrid256 = (NE + 255) / 256;
  const int edgeGridWave = (NE + 3) / 4;
  const int aggGrid = (NN + 3) / 4;

  // ---------- CSR build (by dst) ----------
  hipMemsetAsync(deg, 0, (size_t)NN * sizeof(int), stream);
  hist_k<<<edgeGrid256, 256, 0, stream>>>(dst, deg, NE);
  scan_k<<<1, 1024, 0, stream>>>(deg, rowptr, cursor, NN);
  scatter_k<<<edgeGrid256, 256, 0, stream>>>(src, dst, cursor, csr_src, csr_eid, NE);

  // ---------- conv1 ----------
  gemm_bias<128,128><<<gemmGrid,256,0,stream>>>(x, Wq1, bq1, q, NN);
  gemm_bias<128,128><<<gemmGrid,256,0,stream>>>(x, Wk1, bk1, kbuf, NN);
  gemm_bias<128,128><<<gemmGrid,256,0,stream>>>(x, Wv1, bv1, vbuf, NN);
  gemm_bias<128,32><<<gemmGrid,256,0,stream>>>(x, Ws1, bs1, skip, NN);
  make_wqe_k<128,128,32><<<(129*128+255)/256,256,0,stream>>>(Wq1, bq1, We1, Wqe);
  gemm_bias<128,128><<<gemmGrid,256,0,stream>>>(x, Wqe, Wqe + 128*128, qe, NN);
  edge_logits2_k<128><<<edgeGridWave,256,0,stream>>>(q, kbuf, qe, ea, src, dst,
                                                     logits, NE, 0.1767766953f);
  tconv_agg2_k<128,32,false><<<aggGrid,256,0,stream>>>(
      vbuf, ea, We1, rowptr, csr_src, csr_eid, logits, skip,
      nullptr, nullptr, nullptr, nullptr, h1, NN);

  // ---------- conv2 + fused MLP head ----------
  gemm_bias<32,64><<<gemmGrid,256,0,stream>>>(h1, Wq2, bq2, q, NN);
  gemm_bias<32,64><<<gemmGrid,256,0,stream>>>(h1, Wk2, bk2, kbuf, NN);
  gemm_bias<32,64><<<gemmGrid,256,0,stream>>>(h1, Wv2, bv2, vbuf, NN);
  gemm_bias<32,16><<<gemmGrid,256,0,stream>>>(h1, Ws2, bs2, skip, NN);
  make_wqe_k<32,64,16><<<(33*128+255)/256,256,0,stream>>>(Wq2, bq2, We2, Wqe);
  gemm_bias<32,128><<<gemmGrid,256,0,stream>>>(h1, Wqe, Wqe + 32*128, qe, NN);
  edge_logits2_k<64><<<edgeGridWave,256,0,stream>>>(q, kbuf, qe, ea, src, dst,
                                                    logits, NE, 0.25f);
  tconv_agg2_k<64,16,true><<<aggGrid,256,0,stream>>>(
      vbuf, ea, We2, rowptr, csr_src, csr_eid, logits, skip,
      W3, b3, W4, b4, (float*)d_out, NN);
}

// Round 7
// 1031.227 us; speedup vs baseline: 1.2548x; 1.2548x over previous
//
#include <hip/hip_runtime.h>
#include <hip/hip_bf16.h>

// Graph TransformerConv x2 + MLP head. CSR dst-centric fused edge phase,
// factorized edge-MLP, bf16 gathers:
//   logit = (q·k + (We^T q)·ea)/sqrt(C);  agg = sum(p*v) + We^T sum(p*ea)
// N=50000, E=800000, F_NODE=128, F_EDGE=32, H=4, C1=32, C2=16.

constexpr int NN = 50000;
constexpr int NE = 800000;

__device__ __forceinline__ float bl(unsigned u) { return __uint_as_float(u << 16); }
__device__ __forceinline__ float bh(unsigned u) { return __uint_as_float(u & 0xffff0000u); }
__device__ __forceinline__ unsigned pk2(float a, float b) {
  __hip_bfloat16 x = __float2bfloat16(a), y = __float2bfloat16(b);
  unsigned short ux = *(unsigned short*)&x, uy = *(unsigned short*)&y;
  return (unsigned)ux | ((unsigned)uy << 16);
}
__device__ __forceinline__ void stv(float* p, float v) { *p = v; }
__device__ __forceinline__ void stv(__hip_bfloat16* p, float v) { *p = __float2bfloat16(v); }

// ---- generic small GEMM: C[n,M] = A[n,K] @ W[K,M] + b ----
template <int K, int M, typename OT>
__global__ __launch_bounds__(256) void gemm_bias(
    const float* __restrict__ A, const float* __restrict__ W,
    const float* __restrict__ b, OT* __restrict__ C, int n) {
  constexpr int RB = 64;
  constexpr int RSTEP = 256 / M;
  __shared__ float As[RB][K];
  const int bi = blockIdx.x * RB;
  for (int idx = threadIdx.x; idx < RB * K; idx += 256) {
    int r = idx / K, c = idx - r * K;
    int gr = bi + r;
    As[r][c] = (gr < n) ? A[(size_t)gr * K + c] : 0.f;
  }
  __syncthreads();
  const int col = threadIdx.x % M;
  const int r0 = threadIdx.x / M;
  const float bias = b[col];
  for (int rbase = r0; rbase < RB; rbase += RSTEP * 4) {
    float a0 = bias, a1 = bias, a2 = bias, a3 = bias;
#pragma unroll 8
    for (int kk = 0; kk < K; ++kk) {
      float w = W[kk * M + col];
      a0 = fmaf(As[rbase][kk], w, a0);
      a1 = fmaf(As[rbase + RSTEP][kk], w, a1);
      a2 = fmaf(As[rbase + 2 * RSTEP][kk], w, a2);
      a3 = fmaf(As[rbase + 3 * RSTEP][kk], w, a3);
    }
    if (bi + rbase < n)              stv(&C[(size_t)(bi + rbase) * M + col], a0);
    if (bi + rbase + RSTEP < n)      stv(&C[(size_t)(bi + rbase + RSTEP) * M + col], a1);
    if (bi + rbase + 2 * RSTEP < n)  stv(&C[(size_t)(bi + rbase + 2 * RSTEP) * M + col], a2);
    if (bi + rbase + 3 * RSTEP < n)  stv(&C[(size_t)(bi + rbase + 3 * RSTEP) * M + col], a3);
  }
}

// ---- fold Wq,bq,We into Wqe [(K+1) x 128], col layout h*32+f; last row = bias ----
template <int K, int HC, int C>
__global__ __launch_bounds__(256) void make_wqe_k(
    const float* __restrict__ Wq, const float* __restrict__ bq,
    const float* __restrict__ We, float* __restrict__ Wqe) {
  const int idx = blockIdx.x * 256 + threadIdx.x;
  if (idx >= (K + 1) * 128) return;
  const int r = idx >> 7;
  const int hf = idx & 127;
  const int h = hf >> 5, f = hf & 31;
  float acc = 0.f;
#pragma unroll
  for (int c = 0; c < C; ++c) {
    const float wv = We[f * HC + h * C + c];
    const float qv = (r < K) ? Wq[r * HC + h * C + c] : bq[h * C + c];
    acc = fmaf(qv, wv, acc);
  }
  Wqe[idx] = acc;
}

// ---- CSR build ----
__global__ __launch_bounds__(256) void hist_k(const int* __restrict__ dst,
                                              int* __restrict__ deg, int nE) {
  const int i = blockIdx.x * 256 + threadIdx.x;
  if (i < nE) atomicAdd(&deg[dst[i]], 1);
}

__global__ __launch_bounds__(1024) void scan_k(const int* __restrict__ deg,
                                               int* __restrict__ rowptr,
                                               int* __restrict__ cursor, int n) {
  __shared__ int part[1024];
  const int t = threadIdx.x;
  const int chunk = (n + 1023) / 1024;
  const int lo = t * chunk;
  const int hi = min(lo + chunk, n);
  int s = 0;
  for (int i = lo; i < hi; ++i) s += deg[i];
  part[t] = s;
  __syncthreads();
  for (int off = 1; off < 1024; off <<= 1) {
    int tmp = (t >= off) ? part[t - off] : 0;
    __syncthreads();
    part[t] += tmp;
    __syncthreads();
  }
  int base = (t == 0) ? 0 : part[t - 1];
  for (int i = lo; i < hi; ++i) {
    rowptr[i] = base;
    cursor[i] = base;
    base += deg[i];
  }
  if (t == 1023) rowptr[n] = part[1023];
}

__global__ __launch_bounds__(256) void scatter_k(
    const int* __restrict__ src, const int* __restrict__ dst,
    int* __restrict__ cursor, int* __restrict__ csr_src,
    int* __restrict__ csr_eid, int nE) {
  const int i = blockIdx.x * 256 + threadIdx.x;
  if (i < nE) {
    const int d = dst[i];
    const int pos = atomicAdd(&cursor[d], 1);
    csr_src[pos] = src[i];
    csr_eid[pos] = i;
  }
}

// ---- permute ea into CSR order, convert to bf16 ----
__global__ __launch_bounds__(256) void permute_ea_k(
    const float* __restrict__ ea, const int* __restrict__ csr_eid,
    unsigned* __restrict__ eab, int nE) {
  const int t = blockIdx.x * 256 + threadIdx.x;
  if (t >= nE * 16) return;
  const int pos = t >> 4, fp = t & 15;
  const int eid = csr_eid[pos];
  const float2 v = *(const float2*)&ea[(size_t)eid * 32 + 2 * fp];
  eab[(size_t)pos * 16 + fp] = pk2(v.x, v.y);
}

// ---- fused dst-centric TransformerConv: inline logits + chunked online softmax ----
// One wave per node. 64 lanes = 4 heads x 16 lanes. CPL = HC/64 channels/lane.
template <int HC, int C, bool FINAL>
__global__ __launch_bounds__(256) void tconv_fused_k(
    const float* __restrict__ q, const __hip_bfloat16* __restrict__ kb,
    const __hip_bfloat16* __restrict__ vb, const float* __restrict__ qe,
    const unsigned* __restrict__ eab, const int* __restrict__ rowptr,
    const int* __restrict__ csr_src, const float* __restrict__ We,
    const float* __restrict__ skip, const float* __restrict__ W3,
    const float* __restrict__ b3, const float* __restrict__ W4,
    const float* __restrict__ b4, float* __restrict__ out, int n) {
  const int d = (blockIdx.x * 256 + threadIdx.x) >> 6;
  const int lane = threadIdx.x & 63;
  if (d >= n) return;
  constexpr int CPL = HC / 64;
  const int gl = lane & 15;
  const int ch0 = lane * CPL;

  float q0, q1 = 0.f;
  if constexpr (CPL == 2) {
    const float2 qv = *(const float2*)&q[(size_t)d * HC + ch0];
    q0 = qv.x; q1 = qv.y;
  } else {
    q0 = q[(size_t)d * HC + ch0];
  }
  const float2 qev = *(const float2*)&qe[(size_t)d * 128 + (lane >> 4) * 32 + 2 * gl];
  const float inv = rsqrtf((float)C);

  float m = -INFINITY, sden = 0.f;
  float acc0 = 0.f, acc1 = 0.f, pea0 = 0.f, pea1 = 0.f;
  const int p0 = rowptr[d], p1 = rowptr[d + 1];

  for (int base = p0; base < p1; base += 16) {
    int sl = -1;
    if (base + gl < p1) sl = csr_src[base + gl];   // same across head groups
    float l_l = -INFINITY;
    unsigned vst[16], east[16];
    // phase A: logits (channel-parallel per edge) + stash v/ea words
#pragma unroll
    for (int j = 0; j < 16; ++j) {
      const int snj = __builtin_amdgcn_readfirstlane(__shfl(sl, j));
      const int snm = (snj < 0) ? 0 : snj;
      unsigned ku, vu;
      if constexpr (CPL == 2) {
        ku = *(const unsigned*)(kb + (size_t)snm * HC + ch0);
        vu = *(const unsigned*)(vb + (size_t)snm * HC + ch0);
      } else {
        ku = *(const unsigned short*)(kb + (size_t)snm * HC + ch0);
        vu = *(const unsigned short*)(vb + (size_t)snm * HC + ch0);
      }
      const unsigned eu = eab[(size_t)(base + j) * 16 + gl];
      vst[j] = vu; east[j] = eu;
      float dot;
      if constexpr (CPL == 2) {
        dot = q0 * bl(ku) + q1 * bh(ku);
      } else {
        dot = q0 * __uint_as_float(ku << 16);
      }
      dot = fmaf(qev.x, bl(eu), dot);
      dot = fmaf(qev.y, bh(eu), dot);
#pragma unroll
      for (int off = 1; off < 16; off <<= 1) dot += __shfl_xor(dot, off, 16);
      if (snj >= 0) l_l = (gl == j) ? dot * inv : l_l;
    }
    // chunk softmax (parallel across 16 lanes)
    float cmax = l_l;
#pragma unroll
    for (int off = 1; off < 16; off <<= 1) cmax = fmaxf(cmax, __shfl_xor(cmax, off, 16));
    const float newm = fmaxf(m, cmax);
    const float scale = __expf(m - newm);
    const float p_l = __expf(l_l - newm);   // 0 for invalid lanes
    float csum = p_l;
#pragma unroll
    for (int off = 1; off < 16; off <<= 1) csum += __shfl_xor(csum, off, 16);
    sden = sden * scale + csum;
    acc0 *= scale; acc1 *= scale; pea0 *= scale; pea1 *= scale;
    m = newm;
    // phase B: weighted accumulation from stashed words
#pragma unroll
    for (int j = 0; j < 16; ++j) {
      const float pj = __shfl(p_l, j, 16);
      if constexpr (CPL == 2) {
        acc0 = fmaf(pj, bl(vst[j]), acc0);
        acc1 = fmaf(pj, bh(vst[j]), acc1);
      } else {
        acc0 = fmaf(pj, __uint_as_float(vst[j] << 16), acc0);
      }
      pea0 = fmaf(pj, bl(east[j]), pea0);
      pea1 = fmaf(pj, bh(east[j]), pea1);
    }
  }

  const float rs = (sden > 0.f) ? 1.f / sden : 0.f;
  acc0 *= rs; acc1 *= rs; pea0 *= rs; pea1 *= rs;

  // We^T correction: acc_ch += sum_f We[f, ch] * pea_h[f]
  float cor0 = 0.f, cor1 = 0.f;
#pragma unroll
  for (int ff = 0; ff < 16; ++ff) {
    const float pf0 = __shfl(pea0, ff, 16);
    const float pf1 = __shfl(pea1, ff, 16);
    if constexpr (CPL == 2) {
      const float2 w0 = *(const float2*)&We[(2 * ff) * HC + ch0];
      const float2 w1 = *(const float2*)&We[(2 * ff + 1) * HC + ch0];
      cor0 = fmaf(pf0, w0.x, cor0); cor0 = fmaf(pf1, w1.x, cor0);
      cor1 = fmaf(pf0, w0.y, cor1); cor1 = fmaf(pf1, w1.y, cor1);
    } else {
      cor0 = fmaf(pf0, We[(2 * ff) * HC + ch0], cor0);
      cor0 = fmaf(pf1, We[(2 * ff + 1) * HC + ch0], cor0);
    }
  }
  acc0 += cor0; acc1 += cor1;

  // head-mean across the 4 groups
  acc0 += __shfl_xor(acc0, 16); acc0 += __shfl_xor(acc0, 32);
  if constexpr (CPL == 2) { acc1 += __shfl_xor(acc1, 16); acc1 += __shfl_xor(acc1, 32); }

  if constexpr (!FINAL) {
    if (lane < 16) {
      const int c0 = 2 * lane;
      out[(size_t)d * 32 + c0]     = fmaxf(acc0 * 0.25f + skip[(size_t)d * 32 + c0], 0.f);
      out[(size_t)d * 32 + c0 + 1] = fmaxf(acc1 * 0.25f + skip[(size_t)d * 32 + c0 + 1], 0.f);
    }
  } else {
    const int c = lane & 15;
    const float h2 = fmaxf(acc0 * 0.25f + skip[(size_t)d * 16 + c], 0.f);
    const int j = lane & 31;
    float t3 = b3[j];
#pragma unroll
    for (int cc = 0; cc < 16; ++cc)
      t3 = fmaf(__shfl(h2, cc), W3[cc * 32 + j], t3);
    t3 = fmaxf(t3, 0.f);
    float o0 = t3 * W4[j * 2 + 0];
    float o1 = t3 * W4[j * 2 + 1];
#pragma unroll
    for (int off = 1; off < 32; off <<= 1) {
      o0 += __shfl_xor(o0, off);
      o1 += __shfl_xor(o1, off);
    }
    if (lane == 0) {
      out[(size_t)d * 2 + 0] = o0 + b4[0];
      out[(size_t)d * 2 + 1] = o1 + b4[1];
    }
  }
}

extern "C" void kernel_launch(void* const* d_in, const int* in_sizes, int n_in,
                              void* d_out, int out_size, void* d_ws, size_t ws_size,
                              hipStream_t stream) {
  const float* x   = (const float*)d_in[0];
  const int*   ei  = (const int*)d_in[1];
  const float* ea  = (const float*)d_in[2];
  const float* Wq1 = (const float*)d_in[3];  const float* bq1 = (const float*)d_in[4];
  const float* Wk1 = (const float*)d_in[5];  const float* bk1 = (const float*)d_in[6];
  const float* Wv1 = (const float*)d_in[7];  const float* bv1 = (const float*)d_in[8];
  const float* We1 = (const float*)d_in[9];
  const float* Ws1 = (const float*)d_in[10]; const float* bs1 = (const float*)d_in[11];
  const float* Wq2 = (const float*)d_in[12]; const float* bq2 = (const float*)d_in[13];
  const float* Wk2 = (const float*)d_in[14]; const float* bk2 = (const float*)d_in[15];
  const float* Wv2 = (const float*)d_in[16]; const float* bv2 = (const float*)d_in[17];
  const float* We2 = (const float*)d_in[18];
  const float* Ws2 = (const float*)d_in[19]; const float* bs2 = (const float*)d_in[20];
  const float* W3  = (const float*)d_in[21]; const float* b3  = (const float*)d_in[22];
  const float* W4  = (const float*)d_in[23]; const float* b4  = (const float*)d_in[24];
  const int* src = ei;
  const int* dst = ei + NE;

  // workspace layout (bytes via float units)
  float* wsf  = (float*)d_ws;
  float* q    = wsf;                          // N*128 f32
  float* qe   = q + (size_t)NN * 128;         // N*128 f32
  float* skip = qe + (size_t)NN * 128;        // N*32 f32
  float* h1   = skip + (size_t)NN * 32;       // N*32 f32
  float* Wqe  = h1 + (size_t)NN * 32;         // 129*128 f32
  __hip_bfloat16* kb = (__hip_bfloat16*)(Wqe + 129 * 128);   // N*128 bf16
  __hip_bfloat16* vb = kb + (size_t)NN * 128;                 // N*128 bf16
  unsigned* eab = (unsigned*)(vb + (size_t)NN * 128);         // (E+16)*16 u32 (bf16x2)
  int* deg     = (int*)(eab + (size_t)(NE + 16) * 16);        // N
  int* rowptr  = deg + NN;                    // N+1
  int* cursor  = rowptr + NN + 1;             // N
  int* csr_src = cursor + NN;                 // E+16
  int* csr_eid = csr_src + NE + 16;           // E

  const int gemmGrid = (NN + 63) / 64;
  const int edgeGrid = (NE + 255) / 256;
  const int aggGrid  = (NN + 3) / 4;

  // ---------- CSR build (by dst) ----------
  hipMemsetAsync(deg, 0, (size_t)NN * sizeof(int), stream);
  hist_k<<<edgeGrid, 256, 0, stream>>>(dst, deg, NE);
  scan_k<<<1, 1024, 0, stream>>>(deg, rowptr, cursor, NN);
  scatter_k<<<edgeGrid, 256, 0, stream>>>(src, dst, cursor, csr_src, csr_eid, NE);
  permute_ea_k<<<(NE * 16 + 255) / 256, 256, 0, stream>>>(ea, csr_eid, eab, NE);

  // ---------- conv1 ----------
  gemm_bias<128,128,float><<<gemmGrid,256,0,stream>>>(x, Wq1, bq1, q, NN);
  gemm_bias<128,128,__hip_bfloat16><<<gemmGrid,256,0,stream>>>(x, Wk1, bk1, kb, NN);
  gemm_bias<128,128,__hip_bfloat16><<<gemmGrid,256,0,stream>>>(x, Wv1, bv1, vb, NN);
  gemm_bias<128,32,float><<<gemmGrid,256,0,stream>>>(x, Ws1, bs1, skip, NN);
  make_wqe_k<128,128,32><<<(129*128+255)/256,256,0,stream>>>(Wq1, bq1, We1, Wqe);
  gemm_bias<128,128,float><<<gemmGrid,256,0,stream>>>(x, Wqe, Wqe + 128*128, qe, NN);
  tconv_fused_k<128,32,false><<<aggGrid,256,0,stream>>>(
      q, kb, vb, qe, eab, rowptr, csr_src, We1, skip,
      nullptr, nullptr, nullptr, nullptr, h1, NN);

  // ---------- conv2 + fused MLP head ----------
  gemm_bias<32,64,float><<<gemmGrid,256,0,stream>>>(h1, Wq2, bq2, q, NN);
  gemm_bias<32,64,__hip_bfloat16><<<gemmGrid,256,0,stream>>>(h1, Wk2, bk2, kb, NN);
  gemm_bias<32,64,__hip_bfloat16><<<gemmGrid,256,0,stream>>>(h1, Wv2, bv2, vb, NN);
  gemm_bias<32,16,float><<<gemmGrid,256,0,stream>>>(h1, Ws2, bs2, skip, NN);
  make_wqe_k<32,64,16><<<(33*128+255)/256,256,0,stream>>>(Wq2, bq2, We2, Wqe);
  gemm_bias<32,128,float><<<gemmGrid,256,0,stream>>>(h1, Wqe, Wqe + 32*128, qe, NN);
  tconv_fused_k<64,16,true><<<aggGrid,256,0,stream>>>(
      q, kb, vb, qe, eab, rowptr, csr_src, We2, skip,
      W3, b3, W4, b4, (float*)d_out, NN);
}

// Round 8
// 1020.773 us; speedup vs baseline: 1.2677x; 1.0102x over previous
//
#include <hip/hip_runtime.h>
#include <hip/hip_bf16.h>

// Graph TransformerConv x2 + MLP head. CSR dst-centric fused edge phase,
// factorized edge-MLP, bf16 interleaved k/v gathers, batched-load chunks:
//   logit = (q·k + (We^T q)·ea)/sqrt(C);  agg = sum(p*v) + We^T sum(p*ea)
// N=50000, E=800000, F_NODE=128, F_EDGE=32, H=4, C1=32, C2=16.

constexpr int NN = 50000;
constexpr int NE = 800000;

__device__ __forceinline__ float bl(unsigned u) { return __uint_as_float(u << 16); }
__device__ __forceinline__ float bh(unsigned u) { return __uint_as_float(u & 0xffff0000u); }
__device__ __forceinline__ unsigned pk2(float a, float b) {
  __hip_bfloat16 x = __float2bfloat16(a), y = __float2bfloat16(b);
  unsigned short ux = *(unsigned short*)&x, uy = *(unsigned short*)&y;
  return (unsigned)ux | ((unsigned)uy << 16);
}

// ---- fold Wq,bq,We into Wqe [(K+1) x 128], col layout h*32+f; last row = bias ----
template <int K, int HC, int C>
__global__ __launch_bounds__(256) void make_wqe_k(
    const float* __restrict__ Wq, const float* __restrict__ bq,
    const float* __restrict__ We, float* __restrict__ Wqe) {
  const int idx = blockIdx.x * 256 + threadIdx.x;
  if (idx >= (K + 1) * 128) return;
  const int r = idx >> 7;
  const int hf = idx & 127;
  const int h = hf >> 5, f = hf & 31;
  float acc = 0.f;
#pragma unroll
  for (int c = 0; c < C; ++c) {
    const float wv = We[f * HC + h * C + c];
    const float qv = (r < K) ? Wq[r * HC + h * C + c] : bq[h * C + c];
    acc = fmaf(qv, wv, acc);
  }
  Wqe[idx] = acc;
}

// ---- fused projections: q(f32), kv(bf16x2 interleaved), skip(f32), qe(f32) ----
template <int K, int HC, int CS>
__global__ __launch_bounds__(256) void fused_proj_k(
    const float* __restrict__ A,
    const float* __restrict__ Wq, const float* __restrict__ bq,
    const float* __restrict__ Wk, const float* __restrict__ bk,
    const float* __restrict__ Wv, const float* __restrict__ bv,
    const float* __restrict__ Ws, const float* __restrict__ bs,
    const float* __restrict__ Wqe,
    float* __restrict__ qO, unsigned* __restrict__ kvO,
    float* __restrict__ skipO, float* __restrict__ qeO, int n) {
  constexpr int RB = 64;
  __shared__ float As[RB][K];
  const int bi = blockIdx.x * RB;
  for (int idx = threadIdx.x; idx < RB * K; idx += 256) {
    int r = idx / K, c = idx - r * K;
    int gr = bi + r;
    As[r][c] = (gr < n) ? A[(size_t)gr * K + c] : 0.f;
  }
  __syncthreads();
  const int tid = threadIdx.x;
  // --- q section (M=HC) ---
  {
    constexpr int M = HC; constexpr int RS = 256 / M;
    const int col = tid % M, r0 = tid / M;
    const float bias = bq[col];
    for (int rb = r0; rb < RB; rb += RS * 4) {
      float a0 = bias, a1 = bias, a2 = bias, a3 = bias;
#pragma unroll 8
      for (int kk = 0; kk < K; ++kk) {
        const float w = Wq[kk * M + col];
        a0 = fmaf(As[rb][kk], w, a0);
        a1 = fmaf(As[rb + RS][kk], w, a1);
        a2 = fmaf(As[rb + 2 * RS][kk], w, a2);
        a3 = fmaf(As[rb + 3 * RS][kk], w, a3);
      }
      if (bi + rb < n)          qO[(size_t)(bi + rb) * M + col] = a0;
      if (bi + rb + RS < n)     qO[(size_t)(bi + rb + RS) * M + col] = a1;
      if (bi + rb + 2 * RS < n) qO[(size_t)(bi + rb + 2 * RS) * M + col] = a2;
      if (bi + rb + 3 * RS < n) qO[(size_t)(bi + rb + 3 * RS) * M + col] = a3;
    }
  }
  // --- kv section (M=HC, dual accumulate, interleaved bf16 store) ---
  {
    constexpr int M = HC; constexpr int RS = 256 / M;
    const int col = tid % M, r0 = tid / M;
    const float bk0 = bk[col], bv0 = bv[col];
    for (int rb = r0; rb < RB; rb += RS * 2) {
      float k0 = bk0, k1 = bk0, v0 = bv0, v1 = bv0;
#pragma unroll 8
      for (int kk = 0; kk < K; ++kk) {
        const float wk = Wk[kk * M + col], wv = Wv[kk * M + col];
        k0 = fmaf(As[rb][kk], wk, k0);
        k1 = fmaf(As[rb + RS][kk], wk, k1);
        v0 = fmaf(As[rb][kk], wv, v0);
        v1 = fmaf(As[rb + RS][kk], wv, v1);
      }
      if (bi + rb < n)      kvO[(size_t)(bi + rb) * M + col] = pk2(k0, v0);
      if (bi + rb + RS < n) kvO[(size_t)(bi + rb + RS) * M + col] = pk2(k1, v1);
    }
  }
  // --- skip section (M=CS) ---
  {
    constexpr int M = CS; constexpr int RS = 256 / M;
    const int col = tid % M, r0 = tid / M;
    const float bias = bs[col];
    for (int rb = r0; rb < RB; rb += RS) {
      float a = bias;
#pragma unroll 8
      for (int kk = 0; kk < K; ++kk) a = fmaf(As[rb][kk], Ws[kk * M + col], a);
      if (bi + rb < n) skipO[(size_t)(bi + rb) * M + col] = a;
    }
  }
  // --- qe section (M=128, bias in last row of Wqe) ---
  {
    constexpr int M = 128; constexpr int RS = 2;
    const int col = tid % M, r0 = tid / M;
    const float bias = Wqe[K * 128 + col];
    for (int rb = r0; rb < RB; rb += RS * 4) {
      float a0 = bias, a1 = bias, a2 = bias, a3 = bias;
#pragma unroll 8
      for (int kk = 0; kk < K; ++kk) {
        const float w = Wqe[kk * M + col];
        a0 = fmaf(As[rb][kk], w, a0);
        a1 = fmaf(As[rb + RS][kk], w, a1);
        a2 = fmaf(As[rb + 2 * RS][kk], w, a2);
        a3 = fmaf(As[rb + 3 * RS][kk], w, a3);
      }
      if (bi + rb < n)          qeO[(size_t)(bi + rb) * M + col] = a0;
      if (bi + rb + RS < n)     qeO[(size_t)(bi + rb + RS) * M + col] = a1;
      if (bi + rb + 2 * RS < n) qeO[(size_t)(bi + rb + 2 * RS) * M + col] = a2;
      if (bi + rb + 3 * RS < n) qeO[(size_t)(bi + rb + 3 * RS) * M + col] = a3;
    }
  }
}

// ---- CSR build ----
__global__ __launch_bounds__(256) void hist_k(const int* __restrict__ dst,
                                              int* __restrict__ deg, int nE) {
  const int i = blockIdx.x * 256 + threadIdx.x;
  if (i < nE) atomicAdd(&deg[dst[i]], 1);
}

__global__ __launch_bounds__(1024) void scan_k(const int* __restrict__ deg,
                                               int* __restrict__ rowptr,
                                               int* __restrict__ cursor, int n) {
  __shared__ int part[1024];
  const int t = threadIdx.x;
  const int chunk = (n + 1023) / 1024;
  const int lo = t * chunk;
  const int hi = min(lo + chunk, n);
  int s = 0;
  for (int i = lo; i < hi; ++i) s += deg[i];
  part[t] = s;
  __syncthreads();
  for (int off = 1; off < 1024; off <<= 1) {
    int tmp = (t >= off) ? part[t - off] : 0;
    __syncthreads();
    part[t] += tmp;
    __syncthreads();
  }
  int base = (t == 0) ? 0 : part[t - 1];
  for (int i = lo; i < hi; ++i) {
    rowptr[i] = base;
    cursor[i] = base;
    base += deg[i];
  }
  if (t == 1023) rowptr[n] = part[1023];
}

__global__ __launch_bounds__(256) void scatter_k(
    const int* __restrict__ src, const int* __restrict__ dst,
    int* __restrict__ cursor, int* __restrict__ csr_src,
    int* __restrict__ csr_eid, int nE) {
  const int i = blockIdx.x * 256 + threadIdx.x;
  if (i < nE) {
    const int d = dst[i];
    const int pos = atomicAdd(&cursor[d], 1);
    csr_src[pos] = src[i];
    csr_eid[pos] = i;
  }
}

// ---- permute ea into CSR order, convert to bf16; zero-fill 16-row slack ----
__global__ __launch_bounds__(256) void permute_ea_k(
    const float* __restrict__ ea, const int* __restrict__ csr_eid,
    unsigned* __restrict__ eab, int nE) {
  const int t = blockIdx.x * 256 + threadIdx.x;
  if (t >= (nE + 16) * 16) return;
  const int pos = t >> 4, fp = t & 15;
  if (pos >= nE) { eab[(size_t)pos * 16 + fp] = 0; return; }
  const int eid = csr_eid[pos];
  const float2 v = *(const float2*)&ea[(size_t)eid * 32 + 2 * fp];
  eab[(size_t)pos * 16 + fp] = pk2(v.x, v.y);
}

// ---- fused dst-centric TransformerConv: batched-load chunks, online softmax ----
// One wave per node. 64 lanes = 4 heads x 16 lanes. CPL = HC/64 channels/lane.
template <int HC, int C, bool FINAL>
__global__ __launch_bounds__(256, 4) void tconv_fused_k(
    const float* __restrict__ q, const unsigned* __restrict__ kvb,
    const float* __restrict__ qe, const unsigned* __restrict__ eab,
    const int* __restrict__ rowptr, const int* __restrict__ csr_src,
    const float* __restrict__ We, const float* __restrict__ skip,
    const float* __restrict__ W3, const float* __restrict__ b3,
    const float* __restrict__ W4, const float* __restrict__ b4,
    float* __restrict__ out, int n) {
  int d = (blockIdx.x * 256 + threadIdx.x) >> 6;
  d = __builtin_amdgcn_readfirstlane(d);
  const int lane = threadIdx.x & 63;
  if (d >= n) return;
  constexpr int CPL = HC / 64;
  const int gl = lane & 15;
  const int ch0 = lane * CPL;

  float q0, q1 = 0.f;
  if constexpr (CPL == 2) {
    const float2 qv = *(const float2*)&q[(size_t)d * HC + ch0];
    q0 = qv.x; q1 = qv.y;
  } else {
    q0 = q[(size_t)d * HC + ch0];
  }
  const float2 qev = *(const float2*)&qe[(size_t)d * 128 + (lane >> 4) * 32 + 2 * gl];
  const float inv = rsqrtf((float)C);

  float m = -INFINITY, sden = 0.f;
  float acc0 = 0.f, acc1 = 0.f, pea0 = 0.f, pea1 = 0.f;
  const int p0 = __builtin_amdgcn_readfirstlane(rowptr[d]);
  const int p1 = __builtin_amdgcn_readfirstlane(rowptr[d + 1]);

  for (int base = p0; base < p1; base += 16) {
    const int cnt = min(16, p1 - base);
    // scalar src ids (uniform address -> s_load), clamped for slack safety
    int sn[16];
#pragma unroll
    for (int j = 0; j < 16; ++j) {
      const int s = csr_src[base + j];
      sn[j] = ((unsigned)s < (unsigned)n) ? s : 0;
    }
    // batched gathers: all loads issued before any compute
    unsigned kvx[16], kvy[16], eu[16];
#pragma unroll
    for (int j = 0; j < 16; ++j) {
      if constexpr (CPL == 2) {
        const unsigned long long u =
            *(const unsigned long long*)&kvb[(size_t)sn[j] * HC + ch0];
        kvx[j] = (unsigned)u; kvy[j] = (unsigned)(u >> 32);
      } else {
        kvx[j] = kvb[(size_t)sn[j] * HC + ch0];
        kvy[j] = 0;
      }
    }
#pragma unroll
    for (int j = 0; j < 16; ++j) eu[j] = eab[(size_t)(base + j) * 16 + gl];

    // phase A: logits (channel-parallel per edge, pipelined reduces)
    float l_l = -INFINITY;
#pragma unroll
    for (int j = 0; j < 16; ++j) {
      float dot;
      if constexpr (CPL == 2) {
        dot = q0 * bl(kvx[j]) + q1 * bl(kvy[j]);
      } else {
        dot = q0 * bl(kvx[j]);
      }
      dot = fmaf(qev.x, bl(eu[j]), dot);
      dot = fmaf(qev.y, bh(eu[j]), dot);
#pragma unroll
      for (int off = 1; off < 16; off <<= 1) dot += __shfl_xor(dot, off, 16);
      l_l = (gl == j && j < cnt) ? dot * inv : l_l;
    }
    // chunk softmax (parallel across 16 lanes)
    float cmax = l_l;
#pragma unroll
    for (int off = 1; off < 16; off <<= 1) cmax = fmaxf(cmax, __shfl_xor(cmax, off, 16));
    const float newm = fmaxf(m, cmax);
    const float scale = __expf(m - newm);
    const float p_l = __expf(l_l - newm);   // 0 for invalid lanes
    float csum = p_l;
#pragma unroll
    for (int off = 1; off < 16; off <<= 1) csum += __shfl_xor(csum, off, 16);
    sden = sden * scale + csum;
    acc0 *= scale; acc1 *= scale; pea0 *= scale; pea1 *= scale;
    m = newm;
    // phase B: weighted accumulation from stashed registers
#pragma unroll
    for (int j = 0; j < 16; ++j) {
      const float pj = __shfl(p_l, j, 16);
      if constexpr (CPL == 2) {
        acc0 = fmaf(pj, bh(kvx[j]), acc0);
        acc1 = fmaf(pj, bh(kvy[j]), acc1);
      } else {
        acc0 = fmaf(pj, bh(kvx[j]), acc0);
      }
      pea0 = fmaf(pj, bl(eu[j]), pea0);
      pea1 = fmaf(pj, bh(eu[j]), pea1);
    }
  }

  const float rs = (sden > 0.f) ? 1.f / sden : 0.f;
  acc0 *= rs; acc1 *= rs; pea0 *= rs; pea1 *= rs;

  // We^T correction: acc_ch += sum_f We[f, ch] * pea_h[f]
  float cor0 = 0.f, cor1 = 0.f;
#pragma unroll
  for (int ff = 0; ff < 16; ++ff) {
    const float pf0 = __shfl(pea0, ff, 16);
    const float pf1 = __shfl(pea1, ff, 16);
    if constexpr (CPL == 2) {
      const float2 w0 = *(const float2*)&We[(2 * ff) * HC + ch0];
      const float2 w1 = *(const float2*)&We[(2 * ff + 1) * HC + ch0];
      cor0 = fmaf(pf0, w0.x, cor0); cor0 = fmaf(pf1, w1.x, cor0);
      cor1 = fmaf(pf0, w0.y, cor1); cor1 = fmaf(pf1, w1.y, cor1);
    } else {
      cor0 = fmaf(pf0, We[(2 * ff) * HC + ch0], cor0);
      cor0 = fmaf(pf1, We[(2 * ff + 1) * HC + ch0], cor0);
    }
  }
  acc0 += cor0; acc1 += cor1;

  // head-mean across the 4 groups
  acc0 += __shfl_xor(acc0, 16); acc0 += __shfl_xor(acc0, 32);
  if constexpr (CPL == 2) { acc1 += __shfl_xor(acc1, 16); acc1 += __shfl_xor(acc1, 32); }

  if constexpr (!FINAL) {
    if (lane < 16) {
      const int c0 = 2 * lane;
      out[(size_t)d * 32 + c0]     = fmaxf(acc0 * 0.25f + skip[(size_t)d * 32 + c0], 0.f);
      out[(size_t)d * 32 + c0 + 1] = fmaxf(acc1 * 0.25f + skip[(size_t)d * 32 + c0 + 1], 0.f);
    }
  } else {
    const int c = lane & 15;
    const float h2 = fmaxf(acc0 * 0.25f + skip[(size_t)d * 16 + c], 0.f);
    const int j = lane & 31;
    float t3 = b3[j];
#pragma unroll
    for (int cc = 0; cc < 16; ++cc)
      t3 = fmaf(__shfl(h2, cc), W3[cc * 32 + j], t3);
    t3 = fmaxf(t3, 0.f);
    float o0 = t3 * W4[j * 2 + 0];
    float o1 = t3 * W4[j * 2 + 1];
#pragma unroll
    for (int off = 1; off < 32; off <<= 1) {
      o0 += __shfl_xor(o0, off);
      o1 += __shfl_xor(o1, off);
    }
    if (lane == 0) {
      out[(size_t)d * 2 + 0] = o0 + b4[0];
      out[(size_t)d * 2 + 1] = o1 + b4[1];
    }
  }
}

extern "C" void kernel_launch(void* const* d_in, const int* in_sizes, int n_in,
                              void* d_out, int out_size, void* d_ws, size_t ws_size,
                              hipStream_t stream) {
  const float* x   = (const float*)d_in[0];
  const int*   ei  = (const int*)d_in[1];
  const float* ea  = (const float*)d_in[2];
  const float* Wq1 = (const float*)d_in[3];  const float* bq1 = (const float*)d_in[4];
  const float* Wk1 = (const float*)d_in[5];  const float* bk1 = (const float*)d_in[6];
  const float* Wv1 = (const float*)d_in[7];  const float* bv1 = (const float*)d_in[8];
  const float* We1 = (const float*)d_in[9];
  const float* Ws1 = (const float*)d_in[10]; const float* bs1 = (const float*)d_in[11];
  const float* Wq2 = (const float*)d_in[12]; const float* bq2 = (const float*)d_in[13];
  const float* Wk2 = (const float*)d_in[14]; const float* bk2 = (const float*)d_in[15];
  const float* Wv2 = (const float*)d_in[16]; const float* bv2 = (const float*)d_in[17];
  const float* We2 = (const float*)d_in[18];
  const float* Ws2 = (const float*)d_in[19]; const float* bs2 = (const float*)d_in[20];
  const float* W3  = (const float*)d_in[21]; const float* b3  = (const float*)d_in[22];
  const float* W4  = (const float*)d_in[23]; const float* b4  = (const float*)d_in[24];
  const int* src = ei;
  const int* dst = ei + NE;

  // workspace layout
  float* wsf  = (float*)d_ws;
  float* q    = wsf;                          // N*128 f32
  float* qe   = q + (size_t)NN * 128;         // N*128 f32
  float* skip = qe + (size_t)NN * 128;        // N*32 f32
  float* h1   = skip + (size_t)NN * 32;       // N*32 f32
  float* Wqe  = h1 + (size_t)NN * 32;         // 129*128 f32
  unsigned* kvb = (unsigned*)(Wqe + 129 * 128);          // N*128 u32 (bf16x2)
  unsigned* eab = kvb + (size_t)NN * 128;                // (E+16)*16 u32 (bf16x2)
  int* deg     = (int*)(eab + (size_t)(NE + 16) * 16);   // N
  int* rowptr  = deg + NN;                    // N+1
  int* cursor  = rowptr + NN + 1;             // N
  int* csr_src = cursor + NN;                 // E+16
  int* csr_eid = csr_src + NE + 16;           // E

  const int gemmGrid = (NN + 63) / 64;
  const int edgeGrid = (NE + 255) / 256;
  const int aggGrid  = (NN + 3) / 4;

  // ---------- CSR build (by dst) ----------
  hipMemsetAsync(deg, 0, (size_t)NN * sizeof(int), stream);
  hist_k<<<edgeGrid, 256, 0, stream>>>(dst, deg, NE);
  scan_k<<<1, 1024, 0, stream>>>(deg, rowptr, cursor, NN);
  scatter_k<<<edgeGrid, 256, 0, stream>>>(src, dst, cursor, csr_src, csr_eid, NE);
  permute_ea_k<<<((NE + 16) * 16 + 255) / 256, 256, 0, stream>>>(ea, csr_eid, eab, NE);

  // ---------- conv1 ----------
  make_wqe_k<128,128,32><<<(129*128+255)/256,256,0,stream>>>(Wq1, bq1, We1, Wqe);
  fused_proj_k<128,128,32><<<gemmGrid,256,0,stream>>>(
      x, Wq1, bq1, Wk1, bk1, Wv1, bv1, Ws1, bs1, Wqe, q, kvb, skip, qe, NN);
  tconv_fused_k<128,32,false><<<aggGrid,256,0,stream>>>(
      q, kvb, qe, eab, rowptr, csr_src, We1, skip,
      nullptr, nullptr, nullptr, nullptr, h1, NN);

  // ---------- conv2 + fused MLP head ----------
  make_wqe_k<32,64,16><<<(33*128+255)/256,256,0,stream>>>(Wq2, bq2, We2, Wqe);
  fused_proj_k<32,64,16><<<gemmGrid,256,0,stream>>>(
      h1, Wq2, bq2, Wk2, bk2, Wv2, bv2, Ws2, bs2, Wqe, q, kvb, skip, qe, NN);
  tconv_fused_k<64,16,true><<<aggGrid,256,0,stream>>>(
      q, kvb, qe, eab, rowptr, csr_src, We2, skip,
      W3, b3, W4, b4, (float*)d_out, NN);
}

// Round 10
// 766.333 us; speedup vs baseline: 1.6886x; 1.3320x over previous
//
#include <hip/hip_runtime.h>
#include <hip/hip_bf16.h>

// Graph TransformerConv x2 + MLP head. MFMA bf16 projections + CSR dst-centric
// fused edge phase (factorized edge-MLP, batched bf16 gathers, online softmax).
// N=50000, E=800000, F_NODE=128, F_EDGE=32, H=4, C1=32, C2=16.

constexpr int NN = 50000;
constexpr int NE = 800000;

typedef __attribute__((ext_vector_type(8))) short short8v;
typedef __attribute__((ext_vector_type(4))) float f32x4;

__device__ __forceinline__ float bl(unsigned u) { return __uint_as_float(u << 16); }
__device__ __forceinline__ float bh(unsigned u) { return __uint_as_float(u & 0xffff0000u); }
__device__ __forceinline__ unsigned short bfbits(float v) {
  __hip_bfloat16 t = __float2bfloat16(v);
  return *(unsigned short*)&t;
}
__device__ __forceinline__ unsigned pk2(float a, float b) {
  return (unsigned)bfbits(a) | ((unsigned)bfbits(b) << 16);
}

// ---- fold Wq,bq,We into Wqe [(K+1) x 128], col layout h*32+f; last row = bias ----
template <int K, int HC, int C>
__global__ __launch_bounds__(256) void make_wqe_k(
    const float* __restrict__ Wq, const float* __restrict__ bq,
    const float* __restrict__ We, float* __restrict__ Wqe) {
  const int idx = blockIdx.x * 256 + threadIdx.x;
  if (idx >= (K + 1) * 128) return;
  const int r = idx >> 7;
  const int hf = idx & 127;
  const int h = hf >> 5, f = hf & 31;
  float acc = 0.f;
#pragma unroll
  for (int c = 0; c < C; ++c) {
    const float wv = We[f * HC + h * C + c];
    const float qv = (r < K) ? Wq[r * HC + h * C + c] : bq[h * C + c];
    acc = fmaf(qv, wv, acc);
  }
  Wqe[idx] = acc;
}

// ---- pack weights: WcatT[NOUT][K] bf16 (cols: q|k|v|qe|skip|pad) + bias f32 ----
template <int K, int QN, int CS, int NOUT>
__global__ __launch_bounds__(256) void pack_w_k(
    const float* __restrict__ Wq, const float* __restrict__ bq,
    const float* __restrict__ Wk, const float* __restrict__ bk,
    const float* __restrict__ Wv, const float* __restrict__ bv,
    const float* __restrict__ Ws, const float* __restrict__ bs,
    const float* __restrict__ Wqe,
    unsigned short* __restrict__ WcatT, float* __restrict__ biasCat) {
  const int t = blockIdx.x * 256 + threadIdx.x;
  if (t >= NOUT * K) return;
  const int nc = t / K, k = t % K;
  float w = 0.f, bias = 0.f;
  if (nc < QN)                    { w = Wq[k * QN + nc];            bias = bq[nc]; }
  else if (nc < 2 * QN)           { w = Wk[k * QN + nc - QN];       bias = bk[nc - QN]; }
  else if (nc < 3 * QN)           { w = Wv[k * QN + nc - 2 * QN];   bias = bv[nc - 2 * QN]; }
  else if (nc < 3 * QN + 128)     { w = Wqe[k * 128 + nc - 3 * QN]; bias = Wqe[K * 128 + nc - 3 * QN]; }
  else if (nc < 3 * QN + 128 + CS){ w = Ws[k * CS + nc - 3 * QN - 128]; bias = bs[nc - 3 * QN - 128]; }
  WcatT[(size_t)nc * K + k] = bfbits(w);
  if (k == 0) biasCat[nc] = bias;
}

// ---- f32 -> bf16 convert (4 elems/thread) ----
__global__ __launch_bounds__(256) void cvt_bf16_k(
    const float* __restrict__ in, unsigned short* __restrict__ out, int n4) {
  const int t = blockIdx.x * 256 + threadIdx.x;
  if (t >= n4) return;
  const float4 v = *(const float4*)&in[(size_t)t * 4];
  uint2 o = { pk2(v.x, v.y), pk2(v.z, v.w) };
  *(uint2*)&out[(size_t)t * 4] = o;
}

// ---- MFMA projection GEMM: [n x K](bf16) @ WcatT^T -> column-routed outputs ----
// 128x64 tile, 4 waves, mfma_f32_16x16x32_bf16.
// A frag: row=lane&15, k=(lane>>4)*8+[0..8). C/D: col=lane&15, row=(lane>>4)*4+r.
template <int K, int QN, int CS, int NOUT>
__global__ __launch_bounds__(256) void mfma_proj_k(
    const unsigned short* __restrict__ Ab, const unsigned short* __restrict__ WcatT,
    const float* __restrict__ biasCat, float* __restrict__ qO,
    unsigned short* __restrict__ kbO, unsigned short* __restrict__ vbO,
    float* __restrict__ qeO, float* __restrict__ skipO, int n) {
  constexpr int KP = K + 8;                  // +16B pad: bank-conflict break
  __shared__ __align__(16) unsigned short As[128 * KP];
  __shared__ __align__(16) unsigned short Bs[64 * KP];
  const int bi = blockIdx.x * 128;
  const int n0 = blockIdx.y * 64;
  const int tid = threadIdx.x;
  for (int idx = tid; idx < 128 * (K / 8); idx += 256) {
    const int r = idx / (K / 8), s = idx % (K / 8);
    uint4 val = {0, 0, 0, 0};
    if (bi + r < n) val = *(const uint4*)&Ab[(size_t)(bi + r) * K + s * 8];
    *(uint4*)&As[r * KP + s * 8] = val;
  }
  for (int idx = tid; idx < 64 * (K / 8); idx += 256) {
    const int r = idx / (K / 8), s = idx % (K / 8);
    *(uint4*)&Bs[r * KP + s * 8] = *(const uint4*)&WcatT[(size_t)(n0 + r) * K + s * 8];
  }
  __syncthreads();
  const int w = tid >> 6, lane = tid & 63;
  const int lm = lane & 15, lk = lane >> 4;
  f32x4 acc[2][4];
#pragma unroll
  for (int nt = 0; nt < 4; ++nt) {
    const float bv = biasCat[n0 + nt * 16 + lm];
    acc[0][nt] = {bv, bv, bv, bv};
    acc[1][nt] = {bv, bv, bv, bv};
  }
#pragma unroll
  for (int ks = 0; ks < K / 32; ++ks) {
    const short8v a0 = *(const short8v*)&As[(w * 32 + lm) * KP + ks * 32 + lk * 8];
    const short8v a1 = *(const short8v*)&As[(w * 32 + 16 + lm) * KP + ks * 32 + lk * 8];
#pragma unroll
    for (int nt = 0; nt < 4; ++nt) {
      const short8v b = *(const short8v*)&Bs[(nt * 16 + lm) * KP + ks * 32 + lk * 8];
      acc[0][nt] = __builtin_amdgcn_mfma_f32_16x16x32_bf16(a0, b, acc[0][nt], 0, 0, 0);
      acc[1][nt] = __builtin_amdgcn_mfma_f32_16x16x32_bf16(a1, b, acc[1][nt], 0, 0, 0);
    }
  }
#pragma unroll
  for (int mt = 0; mt < 2; ++mt)
#pragma unroll
    for (int nt = 0; nt < 4; ++nt)
#pragma unroll
      for (int r = 0; r < 4; ++r) {
        const int row = bi + w * 32 + mt * 16 + lk * 4 + r;
        if (row >= n) continue;
        const int c = n0 + nt * 16 + lm;
        const float val = acc[mt][nt][r];
        if (c < QN)                      qO[(size_t)row * QN + c] = val;
        else if (c < 2 * QN)             kbO[(size_t)row * QN + (c - QN)] = bfbits(val);
        else if (c < 3 * QN)             vbO[(size_t)row * QN + (c - 2 * QN)] = bfbits(val);
        else if (c < 3 * QN + 128)       qeO[(size_t)row * 128 + (c - 3 * QN)] = val;
        else if (c < 3 * QN + 128 + CS)  skipO[(size_t)row * CS + (c - 3 * QN - 128)] = val;
      }
}

// ---- CSR build ----
__global__ __launch_bounds__(256) void hist_k(const int* __restrict__ dst,
                                              int* __restrict__ deg, int nE) {
  const int i = blockIdx.x * 256 + threadIdx.x;
  if (i < nE) atomicAdd(&deg[dst[i]], 1);
}

__global__ __launch_bounds__(1024) void scan_k(const int* __restrict__ deg,
                                               int* __restrict__ rowptr,
                                               int* __restrict__ cursor, int n) {
  __shared__ int part[1024];
  const int t = threadIdx.x;
  const int chunk = (n + 1023) / 1024;
  const int lo = t * chunk;
  const int hi = min(lo + chunk, n);
  int s = 0;
  for (int i = lo; i < hi; ++i) s += deg[i];
  part[t] = s;
  __syncthreads();
  for (int off = 1; off < 1024; off <<= 1) {
    int tmp = (t >= off) ? part[t - off] : 0;
    __syncthreads();
    part[t] += tmp;
    __syncthreads();
  }
  int base = (t == 0) ? 0 : part[t - 1];
  for (int i = lo; i < hi; ++i) {
    rowptr[i] = base;
    cursor[i] = base;
    base += deg[i];
  }
  if (t == 1023) rowptr[n] = part[1023];
}

__global__ __launch_bounds__(256) void scatter_k(
    const int* __restrict__ src, const int* __restrict__ dst,
    int* __restrict__ cursor, int* __restrict__ csr_src,
    int* __restrict__ csr_eid, int nE) {
  const int i = blockIdx.x * 256 + threadIdx.x;
  if (i < nE) {
    const int d = dst[i];
    const int pos = atomicAdd(&cursor[d], 1);
    csr_src[pos] = src[i];
    csr_eid[pos] = i;
  }
}

// ---- permute ea into CSR order, convert to bf16; zero-fill 16-row slack ----
__global__ __launch_bounds__(256) void permute_ea_k(
    const float* __restrict__ ea, const int* __restrict__ csr_eid,
    unsigned* __restrict__ eab, int nE) {
  const int t = blockIdx.x * 256 + threadIdx.x;
  if (t >= (nE + 16) * 16) return;
  const int pos = t >> 4, fp = t & 15;
  if (pos >= nE) { eab[(size_t)pos * 16 + fp] = 0; return; }
  const int eid = csr_eid[pos];
  const float2 v = *(const float2*)&ea[(size_t)eid * 32 + 2 * fp];
  eab[(size_t)pos * 16 + fp] = pk2(v.x, v.y);
}

// ---- fused dst-centric TransformerConv: batched-load chunks, online softmax ----
template <int HC, int C, bool FINAL>
__global__ __launch_bounds__(256, 4) void tconv_fused_k(
    const float* __restrict__ q, const unsigned short* __restrict__ kb,
    const unsigned short* __restrict__ vb, const float* __restrict__ qe,
    const unsigned* __restrict__ eab, const int* __restrict__ rowptr,
    const int* __restrict__ csr_src, const float* __restrict__ We,
    const float* __restrict__ skip, const float* __restrict__ W3,
    const float* __restrict__ b3, const float* __restrict__ W4,
    const float* __restrict__ b4, float* __restrict__ outF,
    unsigned* __restrict__ outB, int n) {
  int d = (blockIdx.x * 256 + threadIdx.x) >> 6;
  d = __builtin_amdgcn_readfirstlane(d);
  const int lane = threadIdx.x & 63;
  if (d >= n) return;
  constexpr int CPL = HC / 64;
  const int gl = lane & 15;
  const int ch0 = lane * CPL;

  float q0, q1 = 0.f;
  if constexpr (CPL == 2) {
    const float2 qv = *(const float2*)&q[(size_t)d * HC + ch0];
    q0 = qv.x; q1 = qv.y;
  } else {
    q0 = q[(size_t)d * HC + ch0];
  }
  const float2 qev = *(const float2*)&qe[(size_t)d * 128 + (lane >> 4) * 32 + 2 * gl];
  const float inv = rsqrtf((float)C);

  float m = -INFINITY, sden = 0.f;
  float acc0 = 0.f, acc1 = 0.f, pea0 = 0.f, pea1 = 0.f;
  const int p0 = __builtin_amdgcn_readfirstlane(rowptr[d]);
  const int p1 = __builtin_amdgcn_readfirstlane(rowptr[d + 1]);

  for (int base = p0; base < p1; base += 16) {
    const int cnt = min(16, p1 - base);
    int sn[16];
#pragma unroll
    for (int j = 0; j < 16; ++j) {
      const int s = csr_src[base + j];
      sn[j] = ((unsigned)s < (unsigned)n) ? s : 0;
    }
    unsigned kw[16], vw[16], eu[16];
#pragma unroll
    for (int j = 0; j < 16; ++j) {
      if constexpr (CPL == 2) {
        kw[j] = *(const unsigned*)&kb[(size_t)sn[j] * HC + ch0];
        vw[j] = *(const unsigned*)&vb[(size_t)sn[j] * HC + ch0];
      } else {
        kw[j] = kb[(size_t)sn[j] * HC + ch0];
        vw[j] = vb[(size_t)sn[j] * HC + ch0];
      }
    }
#pragma unroll
    for (int j = 0; j < 16; ++j) eu[j] = eab[(size_t)(base + j) * 16 + gl];

    // phase A: logits (channel-parallel per edge)
    float l_l = -INFINITY;
#pragma unroll
    for (int j = 0; j < 16; ++j) {
      float dot;
      if constexpr (CPL == 2) {
        dot = q0 * bl(kw[j]) + q1 * bh(kw[j]);
      } else {
        dot = q0 * __uint_as_float(kw[j] << 16);
      }
      dot = fmaf(qev.x, bl(eu[j]), dot);
      dot = fmaf(qev.y, bh(eu[j]), dot);
#pragma unroll
      for (int off = 1; off < 16; off <<= 1) dot += __shfl_xor(dot, off, 16);
      l_l = (gl == j && j < cnt) ? dot * inv : l_l;
    }
    // chunk softmax (parallel across 16 lanes)
    float cmax = l_l;
#pragma unroll
    for (int off = 1; off < 16; off <<= 1) cmax = fmaxf(cmax, __shfl_xor(cmax, off, 16));
    const float newm = fmaxf(m, cmax);
    const float scale = __expf(m - newm);
    const float p_l = __expf(l_l - newm);
    float csum = p_l;
#pragma unroll
    for (int off = 1; off < 16; off <<= 1) csum += __shfl_xor(csum, off, 16);
    sden = sden * scale + csum;
    acc0 *= scale; acc1 *= scale; pea0 *= scale; pea1 *= scale;
    m = newm;
    // phase B: weighted accumulation
#pragma unroll
    for (int j = 0; j < 16; ++j) {
      const float pj = __shfl(p_l, j, 16);
      if constexpr (CPL == 2) {
        acc0 = fmaf(pj, bl(vw[j]), acc0);
        acc1 = fmaf(pj, bh(vw[j]), acc1);
      } else {
        acc0 = fmaf(pj, __uint_as_float(vw[j] << 16), acc0);
      }
      pea0 = fmaf(pj, bl(eu[j]), pea0);
      pea1 = fmaf(pj, bh(eu[j]), pea1);
    }
  }

  const float rs = (sden > 0.f) ? 1.f / sden : 0.f;
  acc0 *= rs; acc1 *= rs; pea0 *= rs; pea1 *= rs;

  // We^T correction
  float cor0 = 0.f, cor1 = 0.f;
#pragma unroll
  for (int ff = 0; ff < 16; ++ff) {
    const float pf0 = __shfl(pea0, ff, 16);
    const float pf1 = __shfl(pea1, ff, 16);
    if constexpr (CPL == 2) {
      const float2 w0 = *(const float2*)&We[(2 * ff) * HC + ch0];
      const float2 w1 = *(const float2*)&We[(2 * ff + 1) * HC + ch0];
      cor0 = fmaf(pf0, w0.x, cor0); cor0 = fmaf(pf1, w1.x, cor0);
      cor1 = fmaf(pf0, w0.y, cor1); cor1 = fmaf(pf1, w1.y, cor1);
    } else {
      cor0 = fmaf(pf0, We[(2 * ff) * HC + ch0], cor0);
      cor0 = fmaf(pf1, We[(2 * ff + 1) * HC + ch0], cor0);
    }
  }
  acc0 += cor0; acc1 += cor1;

  // head-mean
  acc0 += __shfl_xor(acc0, 16); acc0 += __shfl_xor(acc0, 32);
  if constexpr (CPL == 2) { acc1 += __shfl_xor(acc1, 16); acc1 += __shfl_xor(acc1, 32); }

  if constexpr (!FINAL) {
    // h1 (bf16): lane l<16 owns channels 2l, 2l+1
    if (lane < 16) {
      const int c0 = 2 * lane;
      const float v0 = fmaxf(acc0 * 0.25f + skip[(size_t)d * 32 + c0], 0.f);
      const float v1 = fmaxf(acc1 * 0.25f + skip[(size_t)d * 32 + c0 + 1], 0.f);
      outB[(size_t)d * 16 + lane] = pk2(v0, v1);
    }
  } else {
    const int c = lane & 15;
    const float h2 = fmaxf(acc0 * 0.25f + skip[(size_t)d * 16 + c], 0.f);
    const int j = lane & 31;
    float t3 = b3[j];
#pragma unroll
    for (int cc = 0; cc < 16; ++cc)
      t3 = fmaf(__shfl(h2, cc), W3[cc * 32 + j], t3);
    t3 = fmaxf(t3, 0.f);
    float o0 = t3 * W4[j * 2 + 0];
    float o1 = t3 * W4[j * 2 + 1];
#pragma unroll
    for (int off = 1; off < 32; off <<= 1) {
      o0 += __shfl_xor(o0, off);
      o1 += __shfl_xor(o1, off);
    }
    if (lane == 0) {
      outF[(size_t)d * 2 + 0] = o0 + b4[0];
      outF[(size_t)d * 2 + 1] = o1 + b4[1];
    }
  }
}

extern "C" void kernel_launch(void* const* d_in, const int* in_sizes, int n_in,
                              void* d_out, int out_size, void* d_ws, size_t ws_size,
                              hipStream_t stream) {
  const float* x   = (const float*)d_in[0];
  const int*   ei  = (const int*)d_in[1];
  const float* ea  = (const float*)d_in[2];
  const float* Wq1 = (const float*)d_in[3];  const float* bq1 = (const float*)d_in[4];
  const float* Wk1 = (const float*)d_in[5];  const float* bk1 = (const float*)d_in[6];
  const float* Wv1 = (const float*)d_in[7];  const float* bv1 = (const float*)d_in[8];
  const float* We1 = (const float*)d_in[9];
  const float* Ws1 = (const float*)d_in[10]; const float* bs1 = (const float*)d_in[11];
  const float* Wq2 = (const float*)d_in[12]; const float* bq2 = (const float*)d_in[13];
  const float* Wk2 = (const float*)d_in[14]; const float* bk2 = (const float*)d_in[15];
  const float* Wv2 = (const float*)d_in[16]; const float* bv2 = (const float*)d_in[17];
  const float* We2 = (const float*)d_in[18];
  const float* Ws2 = (const float*)d_in[19]; const float* bs2 = (const float*)d_in[20];
  const float* W3  = (const float*)d_in[21]; const float* b3  = (const float*)d_in[22];
  const float* W4  = (const float*)d_in[23]; const float* b4  = (const float*)d_in[24];
  const int* src = ei;
  const int* dst = ei + NE;

  // workspace layout
  float* wsf  = (float*)d_ws;
  float* q    = wsf;                          // N*128 f32
  float* qe   = q + (size_t)NN * 128;         // N*128 f32
  float* skip = qe + (size_t)NN * 128;        // N*32 f32
  unsigned* h1b = (unsigned*)(skip + (size_t)NN * 32);   // N*16 u32 = bf16[N][32]
  float* Wqe  = (float*)(h1b + (size_t)NN * 16);         // 129*128 f32
  float* biasCat = Wqe + 129 * 128;           // 576 f32
  unsigned short* WcatT = (unsigned short*)(biasCat + 576);   // 576*128 bf16
  unsigned short* xb = WcatT + 576 * 128;     // N*128 bf16
  unsigned short* kb = xb + (size_t)NN * 128; // N*128 bf16
  unsigned short* vb = kb + (size_t)NN * 128; // N*128 bf16
  unsigned* eab = (unsigned*)(vb + (size_t)NN * 128);    // (E+16)*16 u32
  int* deg     = (int*)(eab + (size_t)(NE + 16) * 16);   // N
  int* rowptr  = deg + NN;                    // N+1
  int* cursor  = rowptr + NN + 1;             // N
  int* csr_src = cursor + NN;                 // E+16
  int* csr_eid = csr_src + NE + 16;           // E

  const int edgeGrid = (NE + 255) / 256;
  const int aggGrid  = (NN + 3) / 4;
  const int projRows = (NN + 127) / 128;      // 391

  // ---------- CSR build (by dst) ----------
  hipMemsetAsync(deg, 0, (size_t)NN * sizeof(int), stream);
  hist_k<<<edgeGrid, 256, 0, stream>>>(dst, deg, NE);
  scan_k<<<1, 1024, 0, stream>>>(deg, rowptr, cursor, NN);
  scatter_k<<<edgeGrid, 256, 0, stream>>>(src, dst, cursor, csr_src, csr_eid, NE);
  permute_ea_k<<<((NE + 16) * 16 + 255) / 256, 256, 0, stream>>>(ea, csr_eid, eab, NE);

  // ---------- conv1 ----------
  make_wqe_k<128,128,32><<<(129*128+255)/256,256,0,stream>>>(Wq1, bq1, We1, Wqe);
  pack_w_k<128,128,32,576><<<(576*128+255)/256,256,0,stream>>>(
      Wq1, bq1, Wk1, bk1, Wv1, bv1, Ws1, bs1, Wqe, WcatT, biasCat);
  cvt_bf16_k<<<(NN*32+255)/256,256,0,stream>>>(x, xb, NN * 32);
  {
    dim3 grid(projRows, 9);
    mfma_proj_k<128,128,32,576><<<grid,256,0,stream>>>(
        xb, WcatT, biasCat, q, kb, vb, qe, skip, NN);
  }
  tconv_fused_k<128,32,false><<<aggGrid,256,0,stream>>>(
      q, kb, vb, qe, eab, rowptr, csr_src, We1, skip,
      nullptr, nullptr, nullptr, nullptr, nullptr, h1b, NN);

  // ---------- conv2 + fused MLP head ----------
  make_wqe_k<32,64,16><<<(33*128+255)/256,256,0,stream>>>(Wq2, bq2, We2, Wqe);
  pack_w_k<32,64,16,384><<<(384*32+255)/256,256,0,stream>>>(
      Wq2, bq2, Wk2, bk2, Wv2, bv2, Ws2, bs2, Wqe, WcatT, biasCat);
  {
    dim3 grid(projRows, 6);
    mfma_proj_k<32,64,16,384><<<grid,256,0,stream>>>(
        (const unsigned short*)h1b, WcatT, biasCat, q, kb, vb, qe, skip, NN);
  }
  tconv_fused_k<64,16,true><<<aggGrid,256,0,stream>>>(
      q, kb, vb, qe, eab, rowptr, csr_src, We2, skip,
      W3, b3, W4, b4, (float*)d_out, nullptr, NN);
}